// Round 7
// baseline (510.696 us; speedup 1.0000x reference)
//
#include <hip/hip_runtime.h>
#include <math.h>

#define NN 50000
#define EE 800000
#define DD 32
#define BSTR 64    // bucket stride (max degree ~45 at Poisson(16); +8 pad fits)
#define NPART 8    // node-range partitions, mapped to XCDs via blockIdx&7
#define CPB 128    // edge chunks per partition (grid = 8*128 = 1024 blocks)

typedef float v2f __attribute__((ext_vector_type(2)));

__device__ inline v2f vmax2(v2f a, v2f b){ v2f r; r[0]=fmaxf(a[0],b[0]); r[1]=fmaxf(a[1],b[1]); return r; }
__device__ inline v2f vmin2(v2f a, v2f b){ v2f r; r[0]=fminf(a[0],b[0]); r[1]=fminf(a[1],b[1]); return r; }

// ---------------- setup kernels ----------------

__global__ __launch_bounds__(256) void k_zero(float* p, int count){
  int i = blockIdx.x*256 + threadIdx.x;
  if (i < count) p[i] = 0.f;
}

// XCD-partitioned one-pass CSR build (R16-proven: cut write-amp 51->~12 MB).
__global__ __launch_bounds__(256) void k_fillcsr(const int* __restrict__ node_in,
                                                 const int* __restrict__ node_out,
                                                 const float* __restrict__ ew,
                                                 int* __restrict__ cursor,
                                                 int2* __restrict__ csr){
  int part  = blockIdx.x & (NPART-1);
  int group = blockIdx.x >> 3;
  const int per = (EE + CPB - 1) / CPB;   // 6250
  int e0 = group * per;
  int e1 = (e0 + per < EE) ? (e0 + per) : EE;
  unsigned lo = (unsigned)part * 6250u;
  unsigned hi = lo + 6250u;
  for (int e = e0 + threadIdx.x; e < e1; e += 256){
    unsigned o = (unsigned)node_out[e];
    if (o >= lo && o < hi){
      int pos = atomicAdd(&cursor[o], 1);
      int2 v; v.x = node_in[e]; v.y = __float_as_int(ew[e]);
      csr[o*BSTR + pos] = v;
    }
  }
}

// ROUND-7: degree counting-sort (descending) -> perm. Blocks of k_layer
// then own 64 nearly-equal-degree nodes: the 8-lane-group scan loop runs
// ~mean(deg) instead of E[max of 64]=~29 trips in lockstep; heavy blocks
// scheduled first (no grid tail). Per-node math untouched -> bit-identical
// outputs (perm only decides WHICH block computes a node).
__global__ __launch_bounds__(256) void k_hist(const int* __restrict__ cursor,
                                              int* __restrict__ bins){
  __shared__ int lh[64];
  int t = threadIdx.x;
  if (t < 64) lh[t] = 0;
  __syncthreads();
  int n = blockIdx.x*256 + t;
  if (n < NN){
    int d = cursor[n]; if (d > 63) d = 63;
    atomicAdd(&lh[d], 1);
  }
  __syncthreads();
  if (t < 64 && lh[t]) atomicAdd(&bins[t], lh[t]);
}

__global__ void k_scan(const int* __restrict__ bins, int* __restrict__ binoff){
  if (threadIdx.x == 0){
    int acc = 0;
    for (int d = 63; d >= 0; --d){ binoff[d] = acc; acc += bins[d]; }
  }
}

__global__ __launch_bounds__(256) void k_scatter(const int* __restrict__ cursor,
                                                 int* __restrict__ binoff,
                                                 int* __restrict__ perm){
  int n = blockIdx.x*256 + threadIdx.x;
  if (n < NN){
    int d = cursor[n]; if (d > 63) d = 63;
    int pos = atomicAdd(&binoff[d], 1);
    perm[pos] = n;
  }
}

// per-node sum(w): 8-lane group per node, coalesced bucket reads, shfl_xor
// reduce; zero the 8-entry pad tail in parallel; block logsum reduce.
__global__ __launch_bounds__(256) void k_sumw(int2* __restrict__ csr,
                                              const int* __restrict__ cursor,
                                              float* __restrict__ deg_w,
                                              float* __restrict__ logsum){
  __shared__ float sf[256];
  int t = threadIdx.x;
  int g = t >> 3, lane = t & 7;
  int n = blockIdx.x*32 + g;
  float s = 0.f;
  if (n < NN){
    int deg = cursor[n];
    int2* row = csr + n*BSTR;
    for (int i = lane; i < deg; i += 8) s += __int_as_float(row[i].y);
    s += __shfl_xor(s, 1);
    s += __shfl_xor(s, 2);
    s += __shfl_xor(s, 4);
    row[deg + lane] = make_int2(0, 0);   // 8 pads, one per lane
    if (lane == 0) deg_w[n] = s;
  }
  sf[t] = (n < NN && lane == 0) ? logf(s + 1.f) : 0.f;
  __syncthreads();
  for (int off = 128; off > 0; off >>= 1){
    if (t < off) sf[t] += sf[t+off];
    __syncthreads();
  }
  if (t == 0) atomicAdd(logsum, sf[0]);
}

// k_prep + k_wt merged (R6). Blocks 0..47: pack per-(layer,wave) weight
// slices in EXACT phase-2 consumption order (R5-proven: contiguous
// monotone s_load stream, k_layer 60->50us). Block 48: rel_input per
// layer, query-part of final MLP, layer-0 W column-sums.
__global__ __launch_bounds__(448) void k_prep2(const float* __restrict__ qw,
                                               const float* __restrict__ rel_W,
                                               const float* __restrict__ rel_b,
                                               const float* __restrict__ W1,
                                               const float* __restrict__ b1,
                                               const float* __restrict__ lin_W,
                                               float* __restrict__ rel6,
                                               float* __restrict__ qc,
                                               float* __restrict__ wcol,
                                               float* __restrict__ Wt){
  if (blockIdx.x < 48){
    int lw = blockIdx.x;         // 0..47 = l*8 + w
    int l = lw >> 3, w = lw & 7;
    int k = threadIdx.x;         // 0..415 used
    if (k >= 416) return;
    int row;
    if (k < 32) row = k;
    else {
      int kk = k - 32;
      int kp = kk / 3, s = kk - kp*3;
      row = 32 + (kp >> 2)*12 + (kp & 3)*3 + s;
    }
    float4 v = *(const float4*)(lin_W + (size_t)l*13312 + row*32 + w*4);
    ((float4*)Wt)[(size_t)lw*416 + k] = v;
  } else {
    int t = threadIdx.x;
    if (t < 192){
      int l = t >> 5, j = t & 31;
      float s = rel_b[t];
      for (int d = 0; d < 32; ++d) s += qw[d] * rel_W[l*1024 + d*32 + j];
      rel6[t] = s;
    } else if (t < 256){
      int j = t - 192;
      float s = b1[j];
      for (int k = 0; k < 32; ++k) s += qw[k] * W1[(32+k)*64 + j];
      qc[j] = s;
    } else if (t < 288){
      int j = t - 256;
      float s = 0.f;
      for (int k = 0; k < 32; ++k) s += lin_W[k*32 + j];   // layer 0, h-part rows
      wcol[j] = s;
    }
  }
}

// ---------------- layer 0 (specialized: boundary input) ----------------
// Round-0 structure; phase-2 weights via packed Wt; perm'd node order.
__global__ __launch_bounds__(512, 6) void k_layer0(const float* __restrict__ rel6,
                                               const int* __restrict__ cursor,
                                               const int2* __restrict__ csr,
                                               const int* __restrict__ hidx,
                                               const float* __restrict__ Wt,
                                               const float* __restrict__ lin_b,
                                               const float* __restrict__ wcol,
                                               const float* __restrict__ deg_w,
                                               const float* __restrict__ logsum,
                                               const int* __restrict__ perm,
                                               float* __restrict__ h_next){
  __shared__ float sh[128*65];
  int tid = threadIdx.x;
  int base = blockIdx.x * 64;
  int hv0 = *hidx;

  // ---- phase 1: scalar aggregation (csr scan only) ----
  {
    int nl   = tid >> 3;
    int quad = tid & 7;
    float4 r4 = ((const float4*)(rel6))[quad];   // layer 0
    int n0 = base + nl;
    int n = perm[(n0 < NN) ? n0 : NN-1];
    int deg = cursor[n];
    int s0 = n*BSTR, s1 = s0 + deg;
    float S1=0.f, S2=0.f, M=-INFINITY, m=INFINITY;

#define ACCS(C) { \
    float w  = __int_as_float(C.y); \
    float hv = (C.x == hv0) ? 0.f : 100.f; \
    float wm = w * hv; \
    S1 += wm; S2 += wm * hv; \
    M = fmaxf(M, wm); m = fminf(m, wm); }

    int2 cA = csr[s0],   cB = csr[s0+1], cC = csr[s0+2], cD = csr[s0+3];
    int e = s0;
    for (; e + 4 <= s1; e += 4){
      int2 nA = csr[e+4], nB = csr[e+5], nC = csr[e+6], nD = csr[e+7];
      ACCS(cA) ACCS(cB) ACCS(cC) ACCS(cD)
      cA = nA; cB = nB; cC = nC; cD = nD;
    }
    if (e < s1){
      ACCS(cA)
      if (e + 1 < s1){
        ACCS(cB)
        if (e + 2 < s1) ACCS(cC)
      }
    }
#undef ACCS

    float bnd = (n == hv0) ? 0.f : 100.f;
    float cntf = (float)(deg + 1);
#define FIN(cc, rc) { \
    float mxv, mnv; \
    if (deg > 0){ \
      float em = (rc >= 0.f) ? rc*M : rc*m; \
      float en = (rc >= 0.f) ? rc*m : rc*M; \
      mxv = fmaxf(em, bnd); mnv = fminf(en, bnd); \
    } else { mxv = bnd; mnv = bnd; } \
    float meanv = (rc*S1 + bnd) / cntf; \
    float sq    = (rc*rc*S2 + bnd*bnd) / cntf; \
    float sdv   = sqrtf(fmaxf(sq - meanv*meanv, 1e-6f)); \
    int d = quad*4 + cc; \
    sh[(d*4+0)*65 + nl] = meanv; \
    sh[(d*4+1)*65 + nl] = mxv; \
    sh[(d*4+2)*65 + nl] = mnv; \
    sh[(d*4+3)*65 + nl] = sdv; }
    FIN(0, r4.x) FIN(1, r4.y) FIN(2, r4.z) FIN(3, r4.w)
#undef FIN
  }
  __syncthreads();

  // ---- phase 2: linear; x-part = bnd * wcol; 3-sum hoist of sc/iv ----
  {
    int lane = tid & 63;
    int grp = __builtin_amdgcn_readfirstlane(tid >> 6);
    int j0 = grp * 4;
    const float* Ww = Wt + (size_t)grp*1664 + 128;   // layer 0 slice, feat part
    int n0 = base + lane;
    int n = perm[(n0 < NN) ? n0 : NN-1];
    float mean = *logsum / (float)NN;
    float sc = logf(deg_w[n] + 1.f) / mean;
    float iv = 1.f / fmaxf(sc, 0.01f);
    float bndn = (n == hv0) ? 0.f : 100.f;
    v2f a01p={0,0}, a23p={0,0}, a01s={0,0}, a23s={0,0}, a01i={0,0}, a23i={0,0};

    for (int kp = 0; kp < 128; ++kp){
      float f = sh[kp*65 + lane];
      const v2f* wp = (const v2f*)(Ww + kp*12);
      v2f fv; fv[0]=f; fv[1]=f;
      a01p += fv*wp[0];  a23p += fv*wp[1];
      a01s += fv*wp[2];  a23s += fv*wp[3];
      a01i += fv*wp[4];  a23i += fv*wp[5];
    }
    v2f sc2; sc2[0]=sc; sc2[1]=sc;
    v2f iv2; iv2[0]=iv; iv2[1]=iv;
    v2f a01 = a01p + sc2*a01s + iv2*a01i;
    v2f a23 = a23p + sc2*a23s + iv2*a23i;
    a01[0] += lin_b[j0+0] + bndn*wcol[j0+0];
    a01[1] += lin_b[j0+1] + bndn*wcol[j0+1];
    a23[0] += lin_b[j0+2] + bndn*wcol[j0+2];
    a23[1] += lin_b[j0+3] + bndn*wcol[j0+3];

    if (n0 < NN){
      float vs[4] = { a01[0], a01[1], a23[0], a23[1] };
      #pragma unroll
      for (int j = 0; j < 4; ++j)
        h_next[n*32 + j0 + j] = fmaxf(vs[j], 0.f);
    }
  }
}

// ---------------- fused per-layer kernel (layers 1..5) ----------------
// Round-5/6 structure (packed-Wt phase 2, fused tdot l=4, fused MLP l=5),
// now with degree-sorted perm'd node order (this round). Rejected levers
// (counter-proven): SW-pipelined gathers (r1 spill, r2 re-sink); smaller
// blocks (r3: non-uniform j0 loses s_loads); phase-2 LDS transpose (r4).
template<int MODE>
__global__ __launch_bounds__(512, 6) void k_layer(const float* __restrict__ h,
                                               const float* __restrict__ rel6,
                                               const int* __restrict__ cursor,
                                               const int2* __restrict__ csr,
                                               const int* __restrict__ hidx,
                                               const float* __restrict__ tdot,
                                               const float* __restrict__ Wt,
                                               const float* __restrict__ lin_b,
                                               const float* __restrict__ deg_w,
                                               const float* __restrict__ logsum,
                                               const int* __restrict__ perm,
                                               float* __restrict__ h_next,
                                               float* __restrict__ pred_out,
                                               const float* __restrict__ qc,
                                               const float* __restrict__ W1,
                                               const float* __restrict__ W2,
                                               const float* __restrict__ b2,
                                               float* __restrict__ out_score,
                                               float* __restrict__ tdot_out,
                                               int l){
  __shared__ float sh[128*65];
  int tid = threadIdx.x;
  int base = blockIdx.x * 64;
  int hv0 = *hidx;

  // ---- phase 1: aggregation (one 8-lane group per node, unroll-4) ----
  {
    int nl   = tid >> 3;
    int quad = tid & 7;
    float4 r4 = ((const float4*)(rel6 + l*32))[quad];
    int n0 = base + nl;
    bool valid = n0 < NN;
    int n = perm[valid ? n0 : NN-1];
    int deg = cursor[n];
    int s0 = n*BSTR, s1 = s0 + deg;
    v2f S1xy={0,0}, S1zw={0,0}, S2xy={0,0}, S2zw={0,0};
    v2f Mxy={-INFINITY,-INFINITY}, Mzw={-INFINITY,-INFINITY};
    v2f mxy={ INFINITY, INFINITY}, mzw={ INFINITY, INFINITY};
    float best=-INFINITY; int bi=NN;

#define ACC1(C, A, T) { \
    float w = __int_as_float(C.y); \
    v2f wv; wv[0]=w; wv[1]=w; \
    v2f axy; axy[0]=A.x; axy[1]=A.y; \
    v2f azw; azw[0]=A.z; azw[1]=A.w; \
    v2f pxy = wv*axy, pzw = wv*azw; \
    S1xy += pxy; S1zw += pzw; \
    S2xy += pxy*axy; S2zw += pzw*azw; \
    Mxy = vmax2(Mxy, pxy); Mzw = vmax2(Mzw, pzw); \
    mxy = vmin2(mxy, pxy); mzw = vmin2(mzw, pzw); \
    if (MODE==2){ \
      float sv = w*T; \
      if (sv > best){ best = sv; bi = C.x; } \
      else if (sv == best && C.x < bi) bi = C.x; \
    } }

    int2 cA = csr[s0],   cB = csr[s0+1], cC = csr[s0+2], cD = csr[s0+3];
    int e = s0;
    for (; e + 4 <= s1; e += 4){
      float4 a  = ((const float4*)(h + cA.x*32))[quad];
      float4 b  = ((const float4*)(h + cB.x*32))[quad];
      float4 c4 = ((const float4*)(h + cC.x*32))[quad];
      float4 d4 = ((const float4*)(h + cD.x*32))[quad];
      float tA=0.f, tB=0.f, tC=0.f, tD=0.f;
      if (MODE==2){ tA = tdot[cA.x]; tB = tdot[cB.x]; tC = tdot[cC.x]; tD = tdot[cD.x]; }
      int2 nA = csr[e+4], nB = csr[e+5], nC = csr[e+6], nD = csr[e+7];
      ACC1(cA, a, tA)
      ACC1(cB, b, tB)
      ACC1(cC, c4, tC)
      ACC1(cD, d4, tD)
      cA = nA; cB = nB; cC = nC; cD = nD;
    }
    if (e < s1){
      float4 a = ((const float4*)(h + cA.x*32))[quad];
      float tA = 0.f; if (MODE==2) tA = tdot[cA.x];
      ACC1(cA, a, tA)
      if (e + 1 < s1){
        float4 b = ((const float4*)(h + cB.x*32))[quad];
        float tB = 0.f; if (MODE==2) tB = tdot[cB.x];
        ACC1(cB, b, tB)
        if (e + 2 < s1){
          float4 c4 = ((const float4*)(h + cC.x*32))[quad];
          float tC = 0.f; if (MODE==2) tC = tdot[cC.x];
          ACC1(cC, c4, tC)
        }
      }
    }
#undef ACC1

    float bnd = (n == hv0) ? 0.f : 100.f;
    float cntf = (float)(deg + 1);
#define FIN(cc, rc, S1c, S2c, Mc, mc) { \
    float mxv, mnv; \
    if (deg > 0){ \
      float em = (rc >= 0.f) ? rc*Mc : rc*mc; \
      float en = (rc >= 0.f) ? rc*mc : rc*Mc; \
      mxv = fmaxf(em, bnd); mnv = fminf(en, bnd); \
    } else { mxv = bnd; mnv = bnd; } \
    float meanv = (rc*S1c + bnd) / cntf; \
    float sq    = (rc*rc*S2c + bnd*bnd) / cntf; \
    float sdv   = sqrtf(fmaxf(sq - meanv*meanv, 1e-6f)); \
    int d = quad*4 + cc; \
    sh[(d*4+0)*65 + nl] = meanv; \
    sh[(d*4+1)*65 + nl] = mxv; \
    sh[(d*4+2)*65 + nl] = mnv; \
    sh[(d*4+3)*65 + nl] = sdv; }
    FIN(0, r4.x, S1xy[0], S2xy[0], Mxy[0], mxy[0])
    FIN(1, r4.y, S1xy[1], S2xy[1], Mxy[1], mxy[1])
    FIN(2, r4.z, S1zw[0], S2zw[0], Mzw[0], mzw[0])
    FIN(3, r4.w, S1zw[1], S2zw[1], Mzw[1], mzw[1])
#undef FIN
    if (MODE==2 && valid && quad == 0){
      float ss = (n == hv0) ? 0.f : 3200.f;   // boundary self-loop row sum, w=1
      if (ss > best){ best = ss; bi = n; }
      else if (ss == best && n < bi) bi = n;
      pred_out[n] = (float)bi;
    }
  }
  __syncthreads();

  // ---- phase 2: linear (8 waves, wave w -> j0 = w*4; node = lane) ----
  // 3-sum hoist: acc = P + sc*S + iv*I applied once at the end.
  {
    int lane = tid & 63;
    int grp = __builtin_amdgcn_readfirstlane(tid >> 6);
    int j0 = grp * 4;
    const float* Ww = Wt + (size_t)(l*8 + grp)*1664;   // packed slice (floats)
    int n0 = base + lane;
    int n = perm[(n0 < NN) ? n0 : NN-1];
    float mean = *logsum / (float)NN;
    float sc = logf(deg_w[n] + 1.f) / mean;
    float iv = 1.f / fmaxf(sc, 0.01f);
    const float4* hr = (const float4*)(h + (size_t)n*32);
    float4 x0=hr[0],x1=hr[1],x2=hr[2],x3=hr[3],x4=hr[4],x5=hr[5],x6=hr[6],x7=hr[7];
    v2f a01p={0,0}, a23p={0,0}, a01s={0,0}, a23s={0,0}, a01i={0,0}, a23i={0,0};

#define KONE(XV, K) { \
    v2f xv2; xv2[0] = XV; xv2[1] = XV; \
    const v2f* wr2 = (const v2f*)(Ww + (K)*4); \
    a01p += xv2 * wr2[0]; \
    a23p += xv2 * wr2[1]; }
#define KQ(X, KB) KONE(X.x, KB+0) KONE(X.y, KB+1) KONE(X.z, KB+2) KONE(X.w, KB+3)
    KQ(x0, 0) KQ(x1, 4) KQ(x2, 8) KQ(x3, 12)
    KQ(x4, 16) KQ(x5, 20) KQ(x6, 24) KQ(x7, 28)
#undef KQ
#undef KONE

    const float* Wf = Ww + 128;   // feat part: 3 float4 per kp, contiguous
    for (int kp = 0; kp < 128; ++kp){
      float f = sh[kp*65 + lane];
      const v2f* wp = (const v2f*)(Wf + kp*12);
      v2f fv; fv[0]=f; fv[1]=f;
      a01p += fv*wp[0];  a23p += fv*wp[1];
      a01s += fv*wp[2];  a23s += fv*wp[3];
      a01i += fv*wp[4];  a23i += fv*wp[5];
    }
    v2f sc2; sc2[0]=sc; sc2[1]=sc;
    v2f iv2; iv2[0]=iv; iv2[1]=iv;
    v2f a01 = a01p + sc2*a01s + iv2*a01i;
    v2f a23 = a23p + sc2*a23s + iv2*a23i;
    a01[0] += lin_b[l*32 + j0 + 0];
    a01[1] += lin_b[l*32 + j0 + 1];
    a23[0] += lin_b[l*32 + j0 + 2];
    a23[1] += lin_b[l*32 + j0 + 3];

    float v0r = fmaxf(a01[0], 0.f), v1r = fmaxf(a01[1], 0.f);
    float v2r = fmaxf(a23[0], 0.f), v3r = fmaxf(a23[1], 0.f);

    if (MODE==0 || MODE==1){
      if (n0 < NN){
        h_next[n*32 + j0 + 0] = v0r;
        h_next[n*32 + j0 + 1] = v1r;
        h_next[n*32 + j0 + 2] = v2r;
        h_next[n*32 + j0 + 3] = v3r;
      }
    }
    if (MODE==1){
      // ---- fused tdot (l=4): stage h5 rows, 64 threads do the 32-dot in
      // k_dot's exact ascending order -> bit-identical tdot ----
      __syncthreads();                    // all phase-2 sh reads complete
      sh[(j0+0)*65 + lane] = v0r;
      sh[(j0+1)*65 + lane] = v1r;
      sh[(j0+2)*65 + lane] = v2r;
      sh[(j0+3)*65 + lane] = v3r;
      __syncthreads();
      if (tid < 64){
        const float* relr = rel6 + 5*32;
        float s = 0.f;
        #pragma unroll
        for (int d = 0; d < 32; ++d) s += sh[d*65 + tid] * relr[d];
        if (base + tid < NN) tdot_out[perm[base + tid]] = s;
      }
    } else if (MODE==2){
      // ---- fused final MLP (l=5): h6 never leaves the block ----
      __syncthreads();                    // all phase-2 sh reads complete
      sh[(j0+0)*65 + lane] = v0r;         // stage h6 rows 0..31 (65-stride)
      sh[(j0+1)*65 + lane] = v1r;
      sh[(j0+2)*65 + lane] = v2r;
      sh[(j0+3)*65 + lane] = v3r;
      __syncthreads();
      int node = tid & 63;
      int grp2 = __builtin_amdgcn_readfirstlane(tid >> 6);   // 0..7
      int jm = grp2*8;                    // wave-uniform -> W1 s_loads
      v2f b0, b1v, b2v, b3;
      b0[0]=qc[jm+0]; b0[1]=qc[jm+1]; b1v[0]=qc[jm+2]; b1v[1]=qc[jm+3];
      b2v[0]=qc[jm+4]; b2v[1]=qc[jm+5]; b3[0]=qc[jm+6]; b3[1]=qc[jm+7];
      for (int k = 0; k < 32; ++k){
        float xv = sh[k*65 + node];
        const v2f* wr = (const v2f*)(W1 + k*64 + jm);
        v2f xv2; xv2[0]=xv; xv2[1]=xv;
        b0 += xv2*wr[0]; b1v += xv2*wr[1]; b2v += xv2*wr[2]; b3 += xv2*wr[3];
      }
      float part = fmaxf(b0[0],0.f)*W2[jm+0] + fmaxf(b0[1],0.f)*W2[jm+1]
                 + fmaxf(b1v[0],0.f)*W2[jm+2] + fmaxf(b1v[1],0.f)*W2[jm+3]
                 + fmaxf(b2v[0],0.f)*W2[jm+4] + fmaxf(b2v[1],0.f)*W2[jm+5]
                 + fmaxf(b3[0],0.f)*W2[jm+6] + fmaxf(b3[1],0.f)*W2[jm+7];
      sh[2080 + node*9 + grp2] = part;    // past the 32 staged rows (2080)
      __syncthreads();
      if (tid < 64){
        float s = b2[0];
        #pragma unroll
        for (int g = 0; g < 8; ++g) s += sh[2080 + tid*9 + g];
        if (base + tid < NN) out_score[perm[base + tid]] = s;
      }
    }
  }
}

// ---------------- host launch ----------------
extern "C" void kernel_launch(void* const* d_in, const int* in_sizes, int n_in,
                              void* d_out, int out_size, void* d_ws, size_t ws_size,
                              hipStream_t stream){
  const int*   node_in  = (const int*)d_in[0];
  const int*   node_out = (const int*)d_in[1];
  const float* ew       = (const float*)d_in[2];
  const int*   hidx     = (const int*)d_in[3];
  const float* qw       = (const float*)d_in[4];
  const float* rel_W    = (const float*)d_in[5];
  const float* rel_b    = (const float*)d_in[6];
  const float* lin_W    = (const float*)d_in[7];
  const float* lin_b    = (const float*)d_in[8];
  const float* W1       = (const float*)d_in[9];
  const float* b1       = (const float*)d_in[10];
  const float* W2       = (const float*)d_in[11];
  const float* b2       = (const float*)d_in[12];
  float* out_score = (float*)d_out;
  float* out_pred  = out_score + NN;

  char* w = (char*)d_ws;
  size_t off = 0;
  auto take = [&](size_t bytes)->char*{
    char* p = w + off;
    off = (off + bytes + 255) & ~(size_t)255;
    return p;
  };
  size_t bucket_elems = (size_t)NN * BSTR;            // int2 entries
  int2*  csr      = (int2*)take(bucket_elems*8);
  // contiguous zero block: cursor | deg_w | logsum(64) | bins(64)
  char*  zb       = take((size_t)NN*4 + (size_t)NN*4 + 512);
  int*   cursor   = (int*)zb;
  float* deg_w    = (float*)(cursor + NN);
  float* logsum   = (float*)(deg_w + NN);
  int*   bins     = (int*)(logsum + 64);
  int zc = NN + NN + 64 + 64;

  float* rel6      = (float*)take(192*4);
  float* qc        = (float*)take(64*4);
  float* wcol      = (float*)take(32*4);
  float* Wt        = (float*)take((size_t)48*416*16);   // packed weights
  int*   binoff    = (int*)take(64*4);
  int*   perm      = (int*)take((size_t)NN*4);
  float* tdot      = (float*)take((size_t)NN*4);
  float* h_a       = (float*)take((size_t)NN*32*4);
  float* h_b       = (float*)take((size_t)NN*32*4);

  int nb  = (NN + 255) / 256;   // 196
  int nsb = (NN + 31) / 32;     // 1563 (k_sumw: 32 nodes/block)
  int nlb = (NN + 63) / 64;     // 782
  k_zero   <<<(zc+255)/256, 256, 0, stream>>>((float*)zb, zc);
  k_fillcsr<<<NPART*CPB, 256, 0, stream>>>(node_in, node_out, ew, cursor, csr);
  k_hist   <<<nb, 256, 0, stream>>>(cursor, bins);
  k_scan   <<<1, 64, 0, stream>>>(bins, binoff);
  k_scatter<<<nb, 256, 0, stream>>>(cursor, binoff, perm);
  k_sumw   <<<nsb, 256, 0, stream>>>(csr, cursor, deg_w, logsum);
  k_prep2  <<<49, 448, 0, stream>>>(qw, rel_W, rel_b, W1, b1, lin_W,
                                    rel6, qc, wcol, Wt);

  // layer 0 (specialized, no h input)
  k_layer0<<<nlb, 512, 0, stream>>>(rel6, cursor, csr, hidx, Wt, lin_b,
                                    wcol, deg_w, logsum, perm, h_a);

  float* hc = h_a;
  float* hn = h_b;
  for (int l = 1; l < 6; ++l){
    if (l == 5){
      k_layer<2><<<nlb, 512, 0, stream>>>(hc, rel6, cursor, csr, hidx, tdot,
                                          Wt, lin_b, deg_w, logsum, perm,
                                          hn, out_pred,
                                          qc, W1, W2, b2, out_score, tdot, l);
    } else if (l == 4){
      k_layer<1><<<nlb, 512, 0, stream>>>(hc, rel6, cursor, csr, hidx, tdot,
                                          Wt, lin_b, deg_w, logsum, perm,
                                          hn, out_pred,
                                          qc, W1, W2, b2, out_score, tdot, l);
    } else {
      k_layer<0><<<nlb, 512, 0, stream>>>(hc, rel6, cursor, csr, hidx, tdot,
                                          Wt, lin_b, deg_w, logsum, perm,
                                          hn, out_pred,
                                          qc, W1, W2, b2, out_score, tdot, l);
    }
    float* t1 = hc; hc = hn; hn = t1;
  }
}

// Round 8
// 376.834 us; speedup vs baseline: 1.3552x; 1.3552x over previous
//
#include <hip/hip_runtime.h>
#include <math.h>

#define NN 50000
#define EE 800000
#define DD 32
#define BSTR 64    // bucket stride (max degree ~45 at Poisson(16); +8 pad fits)
#define NPART 8    // node-range partitions, mapped to XCDs via blockIdx&7
#define CPB 128    // edge chunks per partition (grid = 8*128 = 1024 blocks)

typedef float v2f __attribute__((ext_vector_type(2)));

__device__ inline v2f vmax2(v2f a, v2f b){ v2f r; r[0]=fmaxf(a[0],b[0]); r[1]=fmaxf(a[1],b[1]); return r; }
__device__ inline v2f vmin2(v2f a, v2f b){ v2f r; r[0]=fminf(a[0],b[0]); r[1]=fminf(a[1],b[1]); return r; }

// ---------------- setup kernels ----------------

__global__ __launch_bounds__(256) void k_zero(float* p, int count){
  int i = blockIdx.x*256 + threadIdx.x;
  if (i < count) p[i] = 0.f;
}

// XCD-partitioned one-pass CSR build (R16-proven: cut write-amp 51->~12 MB).
// ROUND-8: int4-vectorized node_out scan (4 edges/thread/iter) -- the scan
// stream is read 8x (once per partition) and was the largest aux kernel;
// 4x fewer scan insts at identical bytes/semantics. Chunk stride padded to
// 6252 (mult of 4) so e0%4==0 keeps int4 loads 16-B aligned. Degree-sort
// REJECTED (r7: k_scatter 132us atomic contention, zero k_layer benefit).
__global__ __launch_bounds__(256) void k_fillcsr(const int* __restrict__ node_in,
                                                 const int* __restrict__ node_out,
                                                 const float* __restrict__ ew,
                                                 int* __restrict__ cursor,
                                                 int2* __restrict__ csr){
  int part  = blockIdx.x & (NPART-1);
  int group = blockIdx.x >> 3;
  const int per = 6252;                   // 128*6252 >= EE, mult of 4
  int e0 = group * per;
  int e1 = (e0 + per < EE) ? (e0 + per) : EE;
  unsigned lo = (unsigned)part * 6250u;
  unsigned hi = lo + 6250u;
  for (int e = e0 + threadIdx.x*4; e < e1; e += 1024){
    int4 o4;
    if (e + 4 <= e1){
      o4 = *(const int4*)(node_out + e);
    } else {
      o4.x = node_out[e];
      o4.y = (e+1 < e1) ? node_out[e+1] : -1;
      o4.z = (e+2 < e1) ? node_out[e+2] : -1;
      o4.w = (e+3 < e1) ? node_out[e+3] : -1;
    }
    int ov[4] = { o4.x, o4.y, o4.z, o4.w };
    #pragma unroll
    for (int j = 0; j < 4; ++j){
      unsigned o = (unsigned)ov[j];
      if (o >= lo && o < hi){
        int pos = atomicAdd(&cursor[o], 1);
        int2 v; v.x = node_in[e+j]; v.y = __float_as_int(ew[e+j]);
        csr[o*BSTR + pos] = v;
      }
    }
  }
}

// per-node sum(w): 8-lane group per node, coalesced bucket reads, shfl_xor
// reduce; zero the 8-entry pad tail in parallel; block logsum reduce.
__global__ __launch_bounds__(256) void k_sumw(int2* __restrict__ csr,
                                              const int* __restrict__ cursor,
                                              float* __restrict__ deg_w,
                                              float* __restrict__ logsum){
  __shared__ float sf[256];
  int t = threadIdx.x;
  int g = t >> 3, lane = t & 7;
  int n = blockIdx.x*32 + g;
  float s = 0.f;
  if (n < NN){
    int deg = cursor[n];
    int2* row = csr + n*BSTR;
    for (int i = lane; i < deg; i += 8) s += __int_as_float(row[i].y);
    s += __shfl_xor(s, 1);
    s += __shfl_xor(s, 2);
    s += __shfl_xor(s, 4);
    row[deg + lane] = make_int2(0, 0);   // 8 pads, one per lane
    if (lane == 0) deg_w[n] = s;
  }
  sf[t] = (n < NN && lane == 0) ? logf(s + 1.f) : 0.f;
  __syncthreads();
  for (int off = 128; off > 0; off >>= 1){
    if (t < off) sf[t] += sf[t+off];
    __syncthreads();
  }
  if (t == 0) atomicAdd(logsum, sf[0]);
}

// k_prep + k_wt merged (R6). Blocks 0..47: pack per-(layer,wave) weight
// slices in EXACT phase-2 consumption order (R5-proven: contiguous
// monotone s_load stream, k_layer 60->50us). Block 48: rel_input per
// layer, query-part of final MLP, layer-0 W column-sums.
__global__ __launch_bounds__(448) void k_prep2(const float* __restrict__ qw,
                                               const float* __restrict__ rel_W,
                                               const float* __restrict__ rel_b,
                                               const float* __restrict__ W1,
                                               const float* __restrict__ b1,
                                               const float* __restrict__ lin_W,
                                               float* __restrict__ rel6,
                                               float* __restrict__ qc,
                                               float* __restrict__ wcol,
                                               float* __restrict__ Wt){
  if (blockIdx.x < 48){
    int lw = blockIdx.x;         // 0..47 = l*8 + w
    int l = lw >> 3, w = lw & 7;
    int k = threadIdx.x;         // 0..415 used
    if (k >= 416) return;
    int row;
    if (k < 32) row = k;
    else {
      int kk = k - 32;
      int kp = kk / 3, s = kk - kp*3;
      row = 32 + (kp >> 2)*12 + (kp & 3)*3 + s;
    }
    float4 v = *(const float4*)(lin_W + (size_t)l*13312 + row*32 + w*4);
    ((float4*)Wt)[(size_t)lw*416 + k] = v;
  } else {
    int t = threadIdx.x;
    if (t < 192){
      int l = t >> 5, j = t & 31;
      float s = rel_b[t];
      for (int d = 0; d < 32; ++d) s += qw[d] * rel_W[l*1024 + d*32 + j];
      rel6[t] = s;
    } else if (t < 256){
      int j = t - 192;
      float s = b1[j];
      for (int k = 0; k < 32; ++k) s += qw[k] * W1[(32+k)*64 + j];
      qc[j] = s;
    } else if (t < 288){
      int j = t - 256;
      float s = 0.f;
      for (int k = 0; k < 32; ++k) s += lin_W[k*32 + j];   // layer 0, h-part rows
      wcol[j] = s;
    }
  }
}

// ---------------- layer 0 (specialized: boundary input) ----------------
// Round-0 structure verbatim; phase-2 weights via packed Wt (layer 0).
__global__ __launch_bounds__(512, 6) void k_layer0(const float* __restrict__ rel6,
                                               const int* __restrict__ cursor,
                                               const int2* __restrict__ csr,
                                               const int* __restrict__ hidx,
                                               const float* __restrict__ Wt,
                                               const float* __restrict__ lin_b,
                                               const float* __restrict__ wcol,
                                               const float* __restrict__ deg_w,
                                               const float* __restrict__ logsum,
                                               float* __restrict__ h_next){
  __shared__ float sh[128*65];
  int tid = threadIdx.x;
  int base = blockIdx.x * 64;
  int hv0 = *hidx;

  // ---- phase 1: scalar aggregation (csr scan only) ----
  {
    int nl   = tid >> 3;
    int quad = tid & 7;
    float4 r4 = ((const float4*)(rel6))[quad];   // layer 0
    int n0 = base + nl;
    int n = (n0 < NN) ? n0 : NN-1;
    int deg = cursor[n];
    int s0 = n*BSTR, s1 = s0 + deg;
    float S1=0.f, S2=0.f, M=-INFINITY, m=INFINITY;

#define ACCS(C) { \
    float w  = __int_as_float(C.y); \
    float hv = (C.x == hv0) ? 0.f : 100.f; \
    float wm = w * hv; \
    S1 += wm; S2 += wm * hv; \
    M = fmaxf(M, wm); m = fminf(m, wm); }

    int2 cA = csr[s0],   cB = csr[s0+1], cC = csr[s0+2], cD = csr[s0+3];
    int e = s0;
    for (; e + 4 <= s1; e += 4){
      int2 nA = csr[e+4], nB = csr[e+5], nC = csr[e+6], nD = csr[e+7];
      ACCS(cA) ACCS(cB) ACCS(cC) ACCS(cD)
      cA = nA; cB = nB; cC = nC; cD = nD;
    }
    if (e < s1){
      ACCS(cA)
      if (e + 1 < s1){
        ACCS(cB)
        if (e + 2 < s1) ACCS(cC)
      }
    }
#undef ACCS

    float bnd = (n == hv0) ? 0.f : 100.f;
    float cntf = (float)(deg + 1);
#define FIN(cc, rc) { \
    float mxv, mnv; \
    if (deg > 0){ \
      float em = (rc >= 0.f) ? rc*M : rc*m; \
      float en = (rc >= 0.f) ? rc*m : rc*M; \
      mxv = fmaxf(em, bnd); mnv = fminf(en, bnd); \
    } else { mxv = bnd; mnv = bnd; } \
    float meanv = (rc*S1 + bnd) / cntf; \
    float sq    = (rc*rc*S2 + bnd*bnd) / cntf; \
    float sdv   = sqrtf(fmaxf(sq - meanv*meanv, 1e-6f)); \
    int d = quad*4 + cc; \
    sh[(d*4+0)*65 + nl] = meanv; \
    sh[(d*4+1)*65 + nl] = mxv; \
    sh[(d*4+2)*65 + nl] = mnv; \
    sh[(d*4+3)*65 + nl] = sdv; }
    FIN(0, r4.x) FIN(1, r4.y) FIN(2, r4.z) FIN(3, r4.w)
#undef FIN
  }
  __syncthreads();

  // ---- phase 2: linear; x-part = bnd * wcol; 3-sum hoist of sc/iv ----
  {
    int lane = tid & 63;
    int grp = __builtin_amdgcn_readfirstlane(tid >> 6);
    int j0 = grp * 4;
    const float* Ww = Wt + (size_t)grp*1664 + 128;   // layer 0 slice, feat part
    int n0 = base + lane;
    int n = (n0 < NN) ? n0 : NN-1;
    float mean = *logsum / (float)NN;
    float sc = logf(deg_w[n] + 1.f) / mean;
    float iv = 1.f / fmaxf(sc, 0.01f);
    float bndn = (n == hv0) ? 0.f : 100.f;
    v2f a01p={0,0}, a23p={0,0}, a01s={0,0}, a23s={0,0}, a01i={0,0}, a23i={0,0};

    for (int kp = 0; kp < 128; ++kp){
      float f = sh[kp*65 + lane];
      const v2f* wp = (const v2f*)(Ww + kp*12);
      v2f fv; fv[0]=f; fv[1]=f;
      a01p += fv*wp[0];  a23p += fv*wp[1];
      a01s += fv*wp[2];  a23s += fv*wp[3];
      a01i += fv*wp[4];  a23i += fv*wp[5];
    }
    v2f sc2; sc2[0]=sc; sc2[1]=sc;
    v2f iv2; iv2[0]=iv; iv2[1]=iv;
    v2f a01 = a01p + sc2*a01s + iv2*a01i;
    v2f a23 = a23p + sc2*a23s + iv2*a23i;
    a01[0] += lin_b[j0+0] + bndn*wcol[j0+0];
    a01[1] += lin_b[j0+1] + bndn*wcol[j0+1];
    a23[0] += lin_b[j0+2] + bndn*wcol[j0+2];
    a23[1] += lin_b[j0+3] + bndn*wcol[j0+3];

    if (n0 < NN){
      float vs[4] = { a01[0], a01[1], a23[0], a23[1] };
      #pragma unroll
      for (int j = 0; j < 4; ++j)
        h_next[n0*32 + j0 + j] = fmaxf(vs[j], 0.f);
    }
  }
}

// ---------------- fused per-layer kernel (layers 1..5) ----------------
// Round-5/6 structure (packed-Wt phase 2 = the R5 win; fused tdot l=4,
// fused final MLP l=5). Rejected levers (counter-proven): SW-pipelined
// gathers (r1 spill, r2 re-sink); smaller blocks (r3: non-uniform j0
// loses s_loads); phase-2 LDS transpose (r4); degree sort (r7: scatter
// contention 132us, zero k_layer benefit).
template<int MODE>
__global__ __launch_bounds__(512, 6) void k_layer(const float* __restrict__ h,
                                               const float* __restrict__ rel6,
                                               const int* __restrict__ cursor,
                                               const int2* __restrict__ csr,
                                               const int* __restrict__ hidx,
                                               const float* __restrict__ tdot,
                                               const float* __restrict__ Wt,
                                               const float* __restrict__ lin_b,
                                               const float* __restrict__ deg_w,
                                               const float* __restrict__ logsum,
                                               float* __restrict__ h_next,
                                               float* __restrict__ pred_out,
                                               const float* __restrict__ qc,
                                               const float* __restrict__ W1,
                                               const float* __restrict__ W2,
                                               const float* __restrict__ b2,
                                               float* __restrict__ out_score,
                                               float* __restrict__ tdot_out,
                                               int l){
  __shared__ float sh[128*65];
  int tid = threadIdx.x;
  int base = blockIdx.x * 64;
  int hv0 = *hidx;

  // ---- phase 1: aggregation (one 8-lane group per node, unroll-4) ----
  {
    int nl   = tid >> 3;
    int quad = tid & 7;
    float4 r4 = ((const float4*)(rel6 + l*32))[quad];
    int n0 = base + nl;
    bool valid = n0 < NN;
    int n = valid ? n0 : NN-1;
    int deg = cursor[n];
    int s0 = n*BSTR, s1 = s0 + deg;
    v2f S1xy={0,0}, S1zw={0,0}, S2xy={0,0}, S2zw={0,0};
    v2f Mxy={-INFINITY,-INFINITY}, Mzw={-INFINITY,-INFINITY};
    v2f mxy={ INFINITY, INFINITY}, mzw={ INFINITY, INFINITY};
    float best=-INFINITY; int bi=NN;

#define ACC1(C, A, T) { \
    float w = __int_as_float(C.y); \
    v2f wv; wv[0]=w; wv[1]=w; \
    v2f axy; axy[0]=A.x; axy[1]=A.y; \
    v2f azw; azw[0]=A.z; azw[1]=A.w; \
    v2f pxy = wv*axy, pzw = wv*azw; \
    S1xy += pxy; S1zw += pzw; \
    S2xy += pxy*axy; S2zw += pzw*azw; \
    Mxy = vmax2(Mxy, pxy); Mzw = vmax2(Mzw, pzw); \
    mxy = vmin2(mxy, pxy); mzw = vmin2(mzw, pzw); \
    if (MODE==2){ \
      float sv = w*T; \
      if (sv > best){ best = sv; bi = C.x; } \
      else if (sv == best && C.x < bi) bi = C.x; \
    } }

    int2 cA = csr[s0],   cB = csr[s0+1], cC = csr[s0+2], cD = csr[s0+3];
    int e = s0;
    for (; e + 4 <= s1; e += 4){
      float4 a  = ((const float4*)(h + cA.x*32))[quad];
      float4 b  = ((const float4*)(h + cB.x*32))[quad];
      float4 c4 = ((const float4*)(h + cC.x*32))[quad];
      float4 d4 = ((const float4*)(h + cD.x*32))[quad];
      float tA=0.f, tB=0.f, tC=0.f, tD=0.f;
      if (MODE==2){ tA = tdot[cA.x]; tB = tdot[cB.x]; tC = tdot[cC.x]; tD = tdot[cD.x]; }
      int2 nA = csr[e+4], nB = csr[e+5], nC = csr[e+6], nD = csr[e+7];
      ACC1(cA, a, tA)
      ACC1(cB, b, tB)
      ACC1(cC, c4, tC)
      ACC1(cD, d4, tD)
      cA = nA; cB = nB; cC = nC; cD = nD;
    }
    if (e < s1){
      float4 a = ((const float4*)(h + cA.x*32))[quad];
      float tA = 0.f; if (MODE==2) tA = tdot[cA.x];
      ACC1(cA, a, tA)
      if (e + 1 < s1){
        float4 b = ((const float4*)(h + cB.x*32))[quad];
        float tB = 0.f; if (MODE==2) tB = tdot[cB.x];
        ACC1(cB, b, tB)
        if (e + 2 < s1){
          float4 c4 = ((const float4*)(h + cC.x*32))[quad];
          float tC = 0.f; if (MODE==2) tC = tdot[cC.x];
          ACC1(cC, c4, tC)
        }
      }
    }
#undef ACC1

    float bnd = (n == hv0) ? 0.f : 100.f;
    float cntf = (float)(deg + 1);
#define FIN(cc, rc, S1c, S2c, Mc, mc) { \
    float mxv, mnv; \
    if (deg > 0){ \
      float em = (rc >= 0.f) ? rc*Mc : rc*mc; \
      float en = (rc >= 0.f) ? rc*mc : rc*Mc; \
      mxv = fmaxf(em, bnd); mnv = fminf(en, bnd); \
    } else { mxv = bnd; mnv = bnd; } \
    float meanv = (rc*S1c + bnd) / cntf; \
    float sq    = (rc*rc*S2c + bnd*bnd) / cntf; \
    float sdv   = sqrtf(fmaxf(sq - meanv*meanv, 1e-6f)); \
    int d = quad*4 + cc; \
    sh[(d*4+0)*65 + nl] = meanv; \
    sh[(d*4+1)*65 + nl] = mxv; \
    sh[(d*4+2)*65 + nl] = mnv; \
    sh[(d*4+3)*65 + nl] = sdv; }
    FIN(0, r4.x, S1xy[0], S2xy[0], Mxy[0], mxy[0])
    FIN(1, r4.y, S1xy[1], S2xy[1], Mxy[1], mxy[1])
    FIN(2, r4.z, S1zw[0], S2zw[0], Mzw[0], mzw[0])
    FIN(3, r4.w, S1zw[1], S2zw[1], Mzw[1], mzw[1])
#undef FIN
    if (MODE==2 && valid && quad == 0){
      float ss = (n == hv0) ? 0.f : 3200.f;   // boundary self-loop row sum, w=1
      if (ss > best){ best = ss; bi = n; }
      else if (ss == best && n < bi) bi = n;
      pred_out[n] = (float)bi;
    }
  }
  __syncthreads();

  // ---- phase 2: linear (8 waves, wave w -> j0 = w*4; node = lane) ----
  // 3-sum hoist: acc = P + sc*S + iv*I applied once at the end.
  {
    int lane = tid & 63;
    int grp = __builtin_amdgcn_readfirstlane(tid >> 6);
    int j0 = grp * 4;
    const float* Ww = Wt + (size_t)(l*8 + grp)*1664;   // packed slice (floats)
    int n0 = base + lane;
    int n = (n0 < NN) ? n0 : NN-1;
    float mean = *logsum / (float)NN;
    float sc = logf(deg_w[n] + 1.f) / mean;
    float iv = 1.f / fmaxf(sc, 0.01f);
    const float4* hr = (const float4*)(h + (size_t)n*32);
    float4 x0=hr[0],x1=hr[1],x2=hr[2],x3=hr[3],x4=hr[4],x5=hr[5],x6=hr[6],x7=hr[7];
    v2f a01p={0,0}, a23p={0,0}, a01s={0,0}, a23s={0,0}, a01i={0,0}, a23i={0,0};

#define KONE(XV, K) { \
    v2f xv2; xv2[0] = XV; xv2[1] = XV; \
    const v2f* wr2 = (const v2f*)(Ww + (K)*4); \
    a01p += xv2 * wr2[0]; \
    a23p += xv2 * wr2[1]; }
#define KQ(X, KB) KONE(X.x, KB+0) KONE(X.y, KB+1) KONE(X.z, KB+2) KONE(X.w, KB+3)
    KQ(x0, 0) KQ(x1, 4) KQ(x2, 8) KQ(x3, 12)
    KQ(x4, 16) KQ(x5, 20) KQ(x6, 24) KQ(x7, 28)
#undef KQ
#undef KONE

    const float* Wf = Ww + 128;   // feat part: 3 float4 per kp, contiguous
    for (int kp = 0; kp < 128; ++kp){
      float f = sh[kp*65 + lane];
      const v2f* wp = (const v2f*)(Wf + kp*12);
      v2f fv; fv[0]=f; fv[1]=f;
      a01p += fv*wp[0];  a23p += fv*wp[1];
      a01s += fv*wp[2];  a23s += fv*wp[3];
      a01i += fv*wp[4];  a23i += fv*wp[5];
    }
    v2f sc2; sc2[0]=sc; sc2[1]=sc;
    v2f iv2; iv2[0]=iv; iv2[1]=iv;
    v2f a01 = a01p + sc2*a01s + iv2*a01i;
    v2f a23 = a23p + sc2*a23s + iv2*a23i;
    a01[0] += lin_b[l*32 + j0 + 0];
    a01[1] += lin_b[l*32 + j0 + 1];
    a23[0] += lin_b[l*32 + j0 + 2];
    a23[1] += lin_b[l*32 + j0 + 3];

    float v0r = fmaxf(a01[0], 0.f), v1r = fmaxf(a01[1], 0.f);
    float v2r = fmaxf(a23[0], 0.f), v3r = fmaxf(a23[1], 0.f);

    if (MODE==0 || MODE==1){
      if (n0 < NN){
        h_next[n0*32 + j0 + 0] = v0r;
        h_next[n0*32 + j0 + 1] = v1r;
        h_next[n0*32 + j0 + 2] = v2r;
        h_next[n0*32 + j0 + 3] = v3r;
      }
    }
    if (MODE==1){
      // ---- fused tdot (l=4): stage h5 rows, 64 threads do the 32-dot in
      // k_dot's exact ascending order -> bit-identical tdot ----
      __syncthreads();                    // all phase-2 sh reads complete
      sh[(j0+0)*65 + lane] = v0r;
      sh[(j0+1)*65 + lane] = v1r;
      sh[(j0+2)*65 + lane] = v2r;
      sh[(j0+3)*65 + lane] = v3r;
      __syncthreads();
      if (tid < 64){
        const float* relr = rel6 + 5*32;
        float s = 0.f;
        #pragma unroll
        for (int d = 0; d < 32; ++d) s += sh[d*65 + tid] * relr[d];
        if (base + tid < NN) tdot_out[base + tid] = s;
      }
    } else if (MODE==2){
      // ---- fused final MLP (l=5): h6 never leaves the block ----
      __syncthreads();                    // all phase-2 sh reads complete
      sh[(j0+0)*65 + lane] = v0r;         // stage h6 rows 0..31 (65-stride)
      sh[(j0+1)*65 + lane] = v1r;
      sh[(j0+2)*65 + lane] = v2r;
      sh[(j0+3)*65 + lane] = v3r;
      __syncthreads();
      int node = tid & 63;
      int grp2 = __builtin_amdgcn_readfirstlane(tid >> 6);   // 0..7
      int jm = grp2*8;                    // wave-uniform -> W1 s_loads
      v2f b0, b1v, b2v, b3;
      b0[0]=qc[jm+0]; b0[1]=qc[jm+1]; b1v[0]=qc[jm+2]; b1v[1]=qc[jm+3];
      b2v[0]=qc[jm+4]; b2v[1]=qc[jm+5]; b3[0]=qc[jm+6]; b3[1]=qc[jm+7];
      for (int k = 0; k < 32; ++k){
        float xv = sh[k*65 + node];
        const v2f* wr = (const v2f*)(W1 + k*64 + jm);
        v2f xv2; xv2[0]=xv; xv2[1]=xv;
        b0 += xv2*wr[0]; b1v += xv2*wr[1]; b2v += xv2*wr[2]; b3 += xv2*wr[3];
      }
      float part = fmaxf(b0[0],0.f)*W2[jm+0] + fmaxf(b0[1],0.f)*W2[jm+1]
                 + fmaxf(b1v[0],0.f)*W2[jm+2] + fmaxf(b1v[1],0.f)*W2[jm+3]
                 + fmaxf(b2v[0],0.f)*W2[jm+4] + fmaxf(b2v[1],0.f)*W2[jm+5]
                 + fmaxf(b3[0],0.f)*W2[jm+6] + fmaxf(b3[1],0.f)*W2[jm+7];
      sh[2080 + node*9 + grp2] = part;    // past the 32 staged rows (2080)
      __syncthreads();
      if (tid < 64){
        float s = b2[0];
        #pragma unroll
        for (int g = 0; g < 8; ++g) s += sh[2080 + tid*9 + g];
        if (base + tid < NN) out_score[base + tid] = s;
      }
    }
  }
}

// ---------------- host launch ----------------
extern "C" void kernel_launch(void* const* d_in, const int* in_sizes, int n_in,
                              void* d_out, int out_size, void* d_ws, size_t ws_size,
                              hipStream_t stream){
  const int*   node_in  = (const int*)d_in[0];
  const int*   node_out = (const int*)d_in[1];
  const float* ew       = (const float*)d_in[2];
  const int*   hidx     = (const int*)d_in[3];
  const float* qw       = (const float*)d_in[4];
  const float* rel_W    = (const float*)d_in[5];
  const float* rel_b    = (const float*)d_in[6];
  const float* lin_W    = (const float*)d_in[7];
  const float* lin_b    = (const float*)d_in[8];
  const float* W1       = (const float*)d_in[9];
  const float* b1       = (const float*)d_in[10];
  const float* W2       = (const float*)d_in[11];
  const float* b2       = (const float*)d_in[12];
  float* out_score = (float*)d_out;
  float* out_pred  = out_score + NN;

  char* w = (char*)d_ws;
  size_t off = 0;
  auto take = [&](size_t bytes)->char*{
    char* p = w + off;
    off = (off + bytes + 255) & ~(size_t)255;
    return p;
  };
  size_t bucket_elems = (size_t)NN * BSTR;            // int2 entries
  int2*  csr      = (int2*)take(bucket_elems*8);
  // contiguous zero block: cursor | deg_w | logsum
  char*  zb       = take((size_t)NN*4 + (size_t)NN*4 + 256);
  int*   cursor   = (int*)zb;
  float* deg_w    = (float*)(cursor + NN);
  float* logsum   = (float*)(deg_w + NN);
  int zc = NN + NN + 64;

  float* rel6      = (float*)take(192*4);
  float* qc        = (float*)take(64*4);
  float* wcol      = (float*)take(32*4);
  float* Wt        = (float*)take((size_t)48*416*16);   // packed weights
  float* tdot      = (float*)take((size_t)NN*4);
  float* h_a       = (float*)take((size_t)NN*32*4);
  float* h_b       = (float*)take((size_t)NN*32*4);

  int nsb = (NN + 31) / 32;     // 1563 (k_sumw: 32 nodes/block)
  int nlb = (NN + 63) / 64;     // 782
  k_zero   <<<(zc+255)/256, 256, 0, stream>>>((float*)zb, zc);
  k_fillcsr<<<NPART*CPB, 256, 0, stream>>>(node_in, node_out, ew, cursor, csr);
  k_sumw   <<<nsb, 256, 0, stream>>>(csr, cursor, deg_w, logsum);
  k_prep2  <<<49, 448, 0, stream>>>(qw, rel_W, rel_b, W1, b1, lin_W,
                                    rel6, qc, wcol, Wt);

  // layer 0 (specialized, no h input)
  k_layer0<<<nlb, 512, 0, stream>>>(rel6, cursor, csr, hidx, Wt, lin_b,
                                    wcol, deg_w, logsum, h_a);

  float* hc = h_a;
  float* hn = h_b;
  for (int l = 1; l < 6; ++l){
    if (l == 5){
      k_layer<2><<<nlb, 512, 0, stream>>>(hc, rel6, cursor, csr, hidx, tdot,
                                          Wt, lin_b, deg_w, logsum,
                                          hn, out_pred,
                                          qc, W1, W2, b2, out_score, tdot, l);
    } else if (l == 4){
      k_layer<1><<<nlb, 512, 0, stream>>>(hc, rel6, cursor, csr, hidx, tdot,
                                          Wt, lin_b, deg_w, logsum,
                                          hn, out_pred,
                                          qc, W1, W2, b2, out_score, tdot, l);
    } else {
      k_layer<0><<<nlb, 512, 0, stream>>>(hc, rel6, cursor, csr, hidx, tdot,
                                          Wt, lin_b, deg_w, logsum,
                                          hn, out_pred,
                                          qc, W1, W2, b2, out_score, tdot, l);
    }
    float* t1 = hc; hc = hn; hn = t1;
  }
}